// Round 3
// baseline (721.815 us; speedup 1.0000x reference)
//
#include <hip/hip_runtime.h>
#include <hip/hip_bf16.h>
#include <math.h>

#define NH 16
#define DH 128
#define DM 2048
#define BB 2
#define TT 2048

typedef unsigned short u16;
typedef __attribute__((ext_vector_type(8))) __bf16 bf16x8;
typedef __attribute__((ext_vector_type(8))) u16 u16x8;
typedef __attribute__((ext_vector_type(4))) u16 u16x4;
typedef __attribute__((ext_vector_type(4))) float f32x4;

__device__ __forceinline__ float bf2f(u16 a){
  union { unsigned u; float f; } v; v.u = ((unsigned)a) << 16; return v.f;
}
__device__ __forceinline__ u16 f2bf(float f){
  union { float f; unsigned u; } v; v.f = f;
  unsigned r = v.u + 0x7fffu + ((v.u >> 16) & 1u);  // RNE
  return (u16)(r >> 16);
}

// ---------------- fp32 -> bf16 elementwise, 4/thread ----------------
__global__ __launch_bounds__(256)
void cvt_f32_bf16(const float* __restrict__ src, u16* __restrict__ dst, int n4){
  const int i = blockIdx.x * 256 + threadIdx.x;
  if (i >= n4) return;
  const f32x4 v = *(const f32x4*)(src + (size_t)i * 4);
  u16x4 o;
  #pragma unroll
  for (int j = 0; j < 4; j++) o[j] = f2bf(v[j]);
  *(u16x4*)(dst + (size_t)i * 4) = o;
}

// ---------------- W fp32 [K,N] -> Wt bf16 [N,K], 2048x2048 ----------------
__global__ __launch_bounds__(256)
void transpose2048(const float* __restrict__ W, u16* __restrict__ Wt){
  __shared__ u16 tile[32][33];
  const int tx = threadIdx.x, ty = threadIdx.y;
  const int bx = blockIdx.x * 32, by = blockIdx.y * 32;
  #pragma unroll
  for (int i = 0; i < 32; i += 8)
    tile[ty + i][tx] = f2bf(W[(size_t)(by + ty + i) * DM + bx + tx]);
  __syncthreads();
  #pragma unroll
  for (int i = 0; i < 32; i += 8)
    Wt[(size_t)(bx + ty + i) * DM + by + tx] = tile[tx][ty + i];
}

// ---------------- Y = A[M,K] * Bt[N,K]^T, bf16 in, fp32 acc ----------------
// mode 1: bf16 out, head layout [B,H,T,DH].  mode 0: fp32 out, [M,N] plain.
__global__ __launch_bounds__(256)
void gemm_bt(const u16* __restrict__ A, const u16* __restrict__ Bt,
             void* __restrict__ C, int mode){
  __shared__ u16 As[128][40];   // +8 pad
  __shared__ u16 Bs[128][40];
  const int tid = threadIdx.x;
  const int wave = tid >> 6, lane = tid & 63;
  const int wm = wave & 1, wn = wave >> 1;
  const int row16 = lane & 15, quad = lane >> 4;
  const int m0 = blockIdx.x * 128, n0 = blockIdx.y * 128;

  const f32x4 zero = {0.f, 0.f, 0.f, 0.f};
  f32x4 acc[4][4];
  #pragma unroll
  for (int i = 0; i < 4; i++)
    #pragma unroll
    for (int j = 0; j < 4; j++) acc[i][j] = zero;

  const int r0 = tid >> 2;          // 0..63
  const int c0 = (tid & 3) * 8;     // 0,8,16,24

  for (int k0 = 0; k0 < DM; k0 += 32){
    const u16* pa = A + (size_t)(m0 + r0) * DM + k0 + c0;
    *(u16x8*)&As[r0][c0]      = *(const u16x8*)pa;
    *(u16x8*)&As[r0 + 64][c0] = *(const u16x8*)(pa + (size_t)64 * DM);
    const u16* pb = Bt + (size_t)(n0 + r0) * DM + k0 + c0;
    *(u16x8*)&Bs[r0][c0]      = *(const u16x8*)pb;
    *(u16x8*)&Bs[r0 + 64][c0] = *(const u16x8*)(pb + (size_t)64 * DM);
    __syncthreads();
    bf16x8 af[4], bfr[4];
    #pragma unroll
    for (int mt = 0; mt < 4; mt++)
      af[mt] = *(const bf16x8*)&As[wm * 64 + mt * 16 + row16][quad * 8];
    #pragma unroll
    for (int nt = 0; nt < 4; nt++)
      bfr[nt] = *(const bf16x8*)&Bs[wn * 64 + nt * 16 + row16][quad * 8];
    #pragma unroll
    for (int mt = 0; mt < 4; mt++)
      #pragma unroll
      for (int nt = 0; nt < 4; nt++)
        acc[mt][nt] = __builtin_amdgcn_mfma_f32_16x16x32_bf16(af[mt], bfr[nt], acc[mt][nt], 0, 0, 0);
    __syncthreads();
  }

  // epilogue: C/D layout row = quad*4+reg, col = lane&15
  #pragma unroll
  for (int mt = 0; mt < 4; mt++){
    #pragma unroll
    for (int nt = 0; nt < 4; nt++){
      #pragma unroll
      for (int r = 0; r < 4; r++){
        const int m = m0 + wm * 64 + mt * 16 + quad * 4 + r;
        const int n = n0 + wn * 64 + nt * 16 + row16;
        if (mode == 1){
          const int b = m >> 11, t = m & (TT - 1);
          const int hh = n >> 7, dh = n & (DH - 1);
          ((u16*)C)[(((size_t)(b * NH + hh) * TT + t) * DH) + dh] = f2bf(acc[mt][nt][r]);
        } else {
          ((float*)C)[(size_t)m * DM + n] = acc[mt][nt][r];
        }
      }
    }
  }
}

// ---------------- in-place RoPE on bf16 [B,H,T,DH] ----------------
__global__ __launch_bounds__(256)
void rope_inplace(u16* buf, const int* __restrict__ posp){
  const int idx = blockIdx.x * 256 + threadIdx.x;   // one per (row, pair)
  const int pair = idx & 63;
  const int row = idx >> 6;                          // b*H*T + h*T + t
  const int t = row & (TT - 1);
  int p0 = *posp; if (p0 < 0) p0 = 0;
  const float inv = expf(-(float)pair * (9.2103403719761836f / 64.f)); // 10000^(-pair/64)
  const float ang = (float)(p0 + t) * inv;
  float sn, cs; sincosf(ang, &sn, &cs);
  const size_t base = (size_t)row * DH;
  const float x1 = bf2f(buf[base + pair]);
  const float x2 = bf2f(buf[base + 64 + pair]);
  buf[base + pair]      = f2bf(x1 * cs - x2 * sn);
  buf[base + 64 + pair] = f2bf(x1 * sn + x2 * cs);
}

// ---------------- causal flash attention (bf16 in, bf16 ctx out [B,T,D]) ----
// grid (T/64, B*H); 4 waves x 16 q-rows; 32-key tiles
__global__ __launch_bounds__(256)
void attn_fwd(const u16* __restrict__ q, const u16* __restrict__ k,
              const u16* __restrict__ v, u16* __restrict__ ctx){
  __shared__ u16 k_s[32][136];     // [key][dh], +8 pad
  __shared__ u16 vt_s[128][40];    // [dh][key], transposed, +8 pad
  __shared__ u16 p_s[4][16][32];   // per-wave P tile [q][key]
  const int tid = threadIdx.x;
  const int wave = tid >> 6, lane = tid & 63;
  const int row16 = lane & 15, quad = lane >> 4;
  const int bh = blockIdx.y;
  const int q0 = blockIdx.x * 64;
  const int qbase = q0 + wave * 16;
  const size_t bho = (size_t)bh * TT * DH;

  bf16x8 qf[4];
  {
    const u16* qp = q + bho + (size_t)(qbase + row16) * DH + quad * 8;
    #pragma unroll
    for (int st = 0; st < 4; st++) qf[st] = *(const bf16x8*)(qp + st * 32);
  }

  float m_r[4], l_r[4];
  #pragma unroll
  for (int r = 0; r < 4; r++){ m_r[r] = -1e30f; l_r[r] = 0.f; }
  const f32x4 zero = {0.f, 0.f, 0.f, 0.f};
  f32x4 o_acc[8];
  #pragma unroll
  for (int i = 0; i < 8; i++) o_acc[i] = zero;

  const float scale = 0.08838834764831845f;  // 1/sqrt(128)
  const int sr = tid >> 3;        // staging key row 0..31
  const int sc = (tid & 7) * 16;  // staging dh base

  for (int kt0 = 0; kt0 < q0 + 64; kt0 += 32){
    const u16* kp = k + bho + (size_t)(kt0 + sr) * DH + sc;
    *(u16x8*)&k_s[sr][sc]     = *(const u16x8*)kp;
    *(u16x8*)&k_s[sr][sc + 8] = *(const u16x8*)(kp + 8);
    const u16* vp = v + bho + (size_t)(kt0 + sr) * DH + sc;
    const u16x8 v0 = *(const u16x8*)vp;
    const u16x8 v1 = *(const u16x8*)(vp + 8);
    #pragma unroll
    for (int j = 0; j < 8; j++){ vt_s[sc + j][sr] = v0[j]; vt_s[sc + 8 + j][sr] = v1[j]; }
    __syncthreads();

    // S = Q K^T : 16 q-rows x 32 keys
    f32x4 s0 = zero, s1 = zero;
    #pragma unroll
    for (int st = 0; st < 4; st++){
      const bf16x8 kf0 = *(const bf16x8*)&k_s[row16][st * 32 + quad * 8];
      const bf16x8 kf1 = *(const bf16x8*)&k_s[16 + row16][st * 32 + quad * 8];
      s0 = __builtin_amdgcn_mfma_f32_16x16x32_bf16(qf[st], kf0, s0, 0, 0, 0);
      s1 = __builtin_amdgcn_mfma_f32_16x16x32_bf16(qf[st], kf1, s1, 0, 0, 0);
    }

    float alpha[4];
    #pragma unroll
    for (int r = 0; r < 4; r++){
      const int qr = qbase + quad * 4 + r;
      const int key0 = kt0 + row16, key1 = kt0 + 16 + row16;
      float a = s0[r] * scale, b = s1[r] * scale;
      if (key0 > qr) a = -3e38f;   // finite mask keeps everything NaN-free
      if (key1 > qr) b = -3e38f;
      float mx = fmaxf(a, b);
      #pragma unroll
      for (int off = 1; off < 16; off <<= 1) mx = fmaxf(mx, __shfl_xor(mx, off, 64));
      const float mn = fmaxf(m_r[r], mx);
      alpha[r] = __expf(m_r[r] - mn);
      const float pa = __expf(a - mn), pb = __expf(b - mn);
      float ps = pa + pb;
      #pragma unroll
      for (int off = 1; off < 16; off <<= 1) ps += __shfl_xor(ps, off, 64);
      l_r[r] = l_r[r] * alpha[r] + ps;
      m_r[r] = mn;
      p_s[wave][quad * 4 + r][row16]      = f2bf(pa);
      p_s[wave][quad * 4 + r][16 + row16] = f2bf(pb);
    }
    #pragma unroll
    for (int nd = 0; nd < 8; nd++)
      #pragma unroll
      for (int r = 0; r < 4; r++) o_acc[nd][r] *= alpha[r];
    __syncthreads();   // order P write -> P read (uniform across block)

    const bf16x8 pf = *(const bf16x8*)&p_s[wave][row16][quad * 8];
    #pragma unroll
    for (int nd = 0; nd < 8; nd++){
      const bf16x8 vb = *(const bf16x8*)&vt_s[nd * 16 + row16][quad * 8];
      o_acc[nd] = __builtin_amdgcn_mfma_f32_16x16x32_bf16(pf, vb, o_acc[nd], 0, 0, 0);
    }
    __syncthreads();   // protect k_s/vt_s restage
  }

  const int b = bh >> 4, h = bh & 15;
  #pragma unroll
  for (int nd = 0; nd < 8; nd++){
    #pragma unroll
    for (int r = 0; r < 4; r++){
      const int qr = qbase + quad * 4 + r;
      const size_t off = ((size_t)b * TT + qr) * DM + h * DH + nd * 16 + row16;
      ctx[off] = f2bf(o_acc[nd][r] / l_r[r]);
    }
  }
}

extern "C" void kernel_launch(void* const* d_in, const int* in_sizes, int n_in,
                              void* d_out, int out_size, void* d_ws, size_t ws_size,
                              hipStream_t stream){
  const float* x  = (const float*)d_in[0];   // fp32 per reference
  const float* wq = (const float*)d_in[1];
  const float* wk = (const float*)d_in[2];
  const float* wv = (const float*)d_in[3];
  const float* wo = (const float*)d_in[4];
  const int* pos  = (const int*)d_in[5];

  char* ws = (char*)d_ws;
  u16* xb = (u16*)ws;                 // 16,777,216 B — bf16 x; dead after QKV gemms
  u16* cb = xb;                       //   ...then reused as ctx buffer
  u16* wt = (u16*)(ws + 16777216);    //  8,388,608 B — one transposed weight (reused)
  u16* qb = (u16*)(ws + 25165824);    // 16,777,216 B each
  u16* kb = qb + 8388608;
  u16* vb = kb + 8388608;             // total ws use: 75,497,472 B

  const dim3 tg(64, 64), tb(32, 8);
  const dim3 gg(32, 16);

  cvt_f32_bf16<<<8192, 256, 0, stream>>>(x, xb, 2097152);

  transpose2048<<<tg, tb, 0, stream>>>(wq, wt);
  gemm_bt<<<gg, 256, 0, stream>>>(xb, wt, qb, 1);
  transpose2048<<<tg, tb, 0, stream>>>(wk, wt);
  gemm_bt<<<gg, 256, 0, stream>>>(xb, wt, kb, 1);
  transpose2048<<<tg, tb, 0, stream>>>(wv, wt);
  gemm_bt<<<gg, 256, 0, stream>>>(xb, wt, vb, 1);

  rope_inplace<<<16384, 256, 0, stream>>>(qb, pos);
  rope_inplace<<<16384, 256, 0, stream>>>(kb, pos);

  attn_fwd<<<dim3(32, 32), 256, 0, stream>>>(qb, kb, vb, cb);

  transpose2048<<<tg, tb, 0, stream>>>(wo, wt);
  gemm_bt<<<gg, 256, 0, stream>>>(cb, wt, d_out, 0);   // fp32 out [B,T,D]
}

// Round 4
// 568.163 us; speedup vs baseline: 1.2704x; 1.2704x over previous
//
#include <hip/hip_runtime.h>
#include <hip/hip_bf16.h>
#include <math.h>

#define NH 16
#define DH 128
#define DM 2048
#define BB 2
#define TT 2048

typedef unsigned short u16;
typedef __attribute__((ext_vector_type(8))) __bf16 bf16x8;
typedef __attribute__((ext_vector_type(8))) u16 u16x8;
typedef __attribute__((ext_vector_type(4))) u16 u16x4;
typedef __attribute__((ext_vector_type(4))) float f32x4;

__device__ __forceinline__ float bf2f(u16 a){
  union { unsigned u; float f; } v; v.u = ((unsigned)a) << 16; return v.f;
}
__device__ __forceinline__ u16 f2bf(float f){
  union { float f; unsigned u; } v; v.f = f;
  unsigned r = v.u + 0x7fffu + ((v.u >> 16) & 1u);  // RNE
  return (u16)(r >> 16);
}

// async global->LDS, 16B per lane. LDS dest is wave-uniform base + lane*16.
typedef const __attribute__((address_space(1))) unsigned int* gas_p;
typedef __attribute__((address_space(3))) unsigned int* las_p;
__device__ __forceinline__ void gl_lds16(const u16* g, u16* lds_uniform_base){
  __builtin_amdgcn_global_load_lds((gas_p)(const void*)g,
                                   (las_p)(void*)lds_uniform_base, 16, 0, 0);
}

// ---------------- fp32 -> bf16 elementwise, 4/thread ----------------
__global__ __launch_bounds__(256)
void cvt_f32_bf16(const float* __restrict__ src, u16* __restrict__ dst, int n4){
  const int i = blockIdx.x * 256 + threadIdx.x;
  if (i >= n4) return;
  const f32x4 v = *(const f32x4*)(src + (size_t)i * 4);
  u16x4 o;
  #pragma unroll
  for (int j = 0; j < 4; j++) o[j] = f2bf(v[j]);
  *(u16x4*)(dst + (size_t)i * 4) = o;
}

// ---------------- W fp32 [K,N] -> Wt bf16 [N,K], 2048x2048 ----------------
__global__ __launch_bounds__(256)
void transpose2048(const float* __restrict__ W, u16* __restrict__ Wt){
  __shared__ u16 tile[32][33];
  const int tx = threadIdx.x, ty = threadIdx.y;
  const int bx = blockIdx.x * 32, by = blockIdx.y * 32;
  #pragma unroll
  for (int i = 0; i < 32; i += 8)
    tile[ty + i][tx] = f2bf(W[(size_t)(by + ty + i) * DM + bx + tx]);
  __syncthreads();
  #pragma unroll
  for (int i = 0; i < 32; i += 8)
    Wt[(size_t)(bx + ty + i) * DM + by + tx] = tile[tx][ty + i];
}

// ---------------- Y = A[M,K] * Bt[N,K]^T, bf16 in, fp32 acc ----------------
// m97 structure: 128x128 tile, BK=32, global_load_lds width=16, unpadded LDS.
// mode 1: bf16 out, head layout [B,H,T,DH].  mode 0: fp32 out, [M,N] plain.
__global__ __launch_bounds__(256)
void gemm_bt(const u16* __restrict__ A, const u16* __restrict__ Bt,
             void* __restrict__ C, int mode){
  __shared__ u16 As[128][32];   // unpadded: required by global_load_lds lane map
  __shared__ u16 Bs[128][32];
  const int tid = threadIdx.x;
  const int wave = tid >> 6, lane = tid & 63;
  const int wm = wave & 1, wn = wave >> 1;
  const int row16 = lane & 15, quad = lane >> 4;
  const int m0 = blockIdx.x * 128, n0 = blockIdx.y * 128;

  const f32x4 zero = {0.f, 0.f, 0.f, 0.f};
  f32x4 acc[4][4];
  #pragma unroll
  for (int i = 0; i < 4; i++)
    #pragma unroll
    for (int j = 0; j < 4; j++) acc[i][j] = zero;

  // staging: wave w covers rows [32w,32w+32) in 2 instrs of 16 rows (1KB each)
  const int srow = (lane >> 2);           // 0..15 within chunk
  const int scol = (lane & 3) * 8;        // u16 units, 16B per lane

  for (int k0 = 0; k0 < DM; k0 += 32){
    #pragma unroll
    for (int c = 0; c < 2; c++){
      const int rbase = wave * 32 + c * 16;
      gl_lds16(A  + (size_t)(m0 + rbase + srow) * DM + k0 + scol, &As[rbase][0]);
      gl_lds16(Bt + (size_t)(n0 + rbase + srow) * DM + k0 + scol, &Bs[rbase][0]);
    }
    __syncthreads();   // compiler emits vmcnt(0) drain before barrier
    bf16x8 af[4], bfr[4];
    #pragma unroll
    for (int mt = 0; mt < 4; mt++)
      af[mt] = *(const bf16x8*)&As[wm * 64 + mt * 16 + row16][quad * 8];
    #pragma unroll
    for (int nt = 0; nt < 4; nt++)
      bfr[nt] = *(const bf16x8*)&Bs[wn * 64 + nt * 16 + row16][quad * 8];
    #pragma unroll
    for (int mt = 0; mt < 4; mt++)
      #pragma unroll
      for (int nt = 0; nt < 4; nt++)
        acc[mt][nt] = __builtin_amdgcn_mfma_f32_16x16x32_bf16(af[mt], bfr[nt], acc[mt][nt], 0, 0, 0);
    __syncthreads();
  }

  // epilogue: C/D layout row = quad*4+reg, col = lane&15
  #pragma unroll
  for (int mt = 0; mt < 4; mt++){
    #pragma unroll
    for (int nt = 0; nt < 4; nt++){
      #pragma unroll
      for (int r = 0; r < 4; r++){
        const int m = m0 + wm * 64 + mt * 16 + quad * 4 + r;
        const int n = n0 + wn * 64 + nt * 16 + row16;
        if (mode == 1){
          const int b = m >> 11, t = m & (TT - 1);
          const int hh = n >> 7, dh = n & (DH - 1);
          ((u16*)C)[(((size_t)(b * NH + hh) * TT + t) * DH) + dh] = f2bf(acc[mt][nt][r]);
        } else {
          ((float*)C)[(size_t)m * DM + n] = acc[mt][nt][r];
        }
      }
    }
  }
}

// ---------------- in-place RoPE on bf16 [B,H,T,DH] ----------------
__global__ __launch_bounds__(256)
void rope_inplace(u16* buf, const int* __restrict__ posp){
  const int idx = blockIdx.x * 256 + threadIdx.x;   // one per (row, pair)
  const int pair = idx & 63;
  const int row = idx >> 6;                          // b*H*T + h*T + t
  const int t = row & (TT - 1);
  int p0 = *posp; if (p0 < 0) p0 = 0;
  const float inv = expf(-(float)pair * (9.2103403719761836f / 64.f)); // 10000^(-pair/64)
  const float ang = (float)(p0 + t) * inv;
  float sn, cs; sincosf(ang, &sn, &cs);
  const size_t base = (size_t)row * DH;
  const float x1 = bf2f(buf[base + pair]);
  const float x2 = bf2f(buf[base + 64 + pair]);
  buf[base + pair]      = f2bf(x1 * cs - x2 * sn);
  buf[base + 64 + pair] = f2bf(x1 * sn + x2 * cs);
}

// ---------------- causal flash attention v2 ----------------
// grid (32 q-tiles reversed, B*H); 4 waves x 16 q-rows (64/block); 64-key tiles.
// K staged natural [key][dh]; V staged transposed via coalesced scalar gather +
// ds_write_b128 (conflict-free bank tiling); P via per-wave LDS (no barrier).
__global__ __launch_bounds__(256)
void attn_fwd(const u16* __restrict__ q, const u16* __restrict__ k,
              const u16* __restrict__ v, u16* __restrict__ ctx){
  __shared__ u16 k_s[64][136];     // 272B rows (16B-aligned), 2-way max
  __shared__ u16 vt_s[128][72];    // [dh][key], 144B rows
  __shared__ u16 p_s[4][16][72];   // per-wave P [q][key]
  const int tid = threadIdx.x;
  const int wave = tid >> 6, lane = tid & 63;
  const int row16 = lane & 15, quad = lane >> 4;
  const int bh = blockIdx.y;
  const int q0 = (31 - blockIdx.x) * 64;   // reversed: heavy blocks dispatch first
  const int qbase = q0 + wave * 16;
  const size_t bho = (size_t)bh * TT * DH;

  bf16x8 qf[4];
  {
    const u16* qp = q + bho + (size_t)(qbase + row16) * DH + quad * 8;
    #pragma unroll
    for (int st = 0; st < 4; st++) qf[st] = *(const bf16x8*)(qp + st * 32);
  }

  float m_r[4], l_r[4];
  #pragma unroll
  for (int r = 0; r < 4; r++){ m_r[r] = -1e30f; l_r[r] = 0.f; }
  const f32x4 zero = {0.f, 0.f, 0.f, 0.f};
  f32x4 o_acc[8];
  #pragma unroll
  for (int i = 0; i < 8; i++) o_acc[i] = zero;

  const float scale = 0.08838834764831845f;  // 1/sqrt(128)
  const int r_ = tid >> 3;        // 0..31: K staging key row
  const int c_ = (tid & 7) * 16;  // K staging dh base

  for (int kt0 = 0; kt0 < q0 + 64; kt0 += 64){
    // ---- stage K natural: 2 parts x 2 b128 each ----
    #pragma unroll
    for (int part = 0; part < 2; part++){
      const int key = r_ + part * 32;
      const u16* kp = k + bho + (size_t)(kt0 + key) * DH + c_;
      *(u16x8*)&k_s[key][c_]     = *(const u16x8*)kp;
      *(u16x8*)&k_s[key][c_ + 8] = *(const u16x8*)(kp + 8);
    }
    // ---- stage V transposed: coalesced scalar gather + b128 write ----
    #pragma unroll
    for (int part = 0; part < 4; part++){
      const int dh = (part & 1) * 64 + lane;
      const int kg = wave + (part >> 1) * 4;
      const u16* vp = v + bho + (size_t)(kt0 + kg * 8) * DH + dh;
      u16x8 tmp;
      #pragma unroll
      for (int j = 0; j < 8; j++) tmp[j] = vp[(size_t)j * DH];
      *(u16x8*)&vt_s[dh][kg * 8] = tmp;
    }
    __syncthreads();

    // ---- S = Q K^T : 16 q-rows x 64 keys per wave ----
    f32x4 s_acc[4];
    #pragma unroll
    for (int nt = 0; nt < 4; nt++) s_acc[nt] = zero;
    #pragma unroll
    for (int st = 0; st < 4; st++){
      #pragma unroll
      for (int nt = 0; nt < 4; nt++){
        const bf16x8 kf = *(const bf16x8*)&k_s[nt * 16 + row16][st * 32 + quad * 8];
        s_acc[nt] = __builtin_amdgcn_mfma_f32_16x16x32_bf16(qf[st], kf, s_acc[nt], 0, 0, 0);
      }
    }

    // ---- online softmax (16-lane groups); P -> per-wave LDS ----
    float alpha[4];
    #pragma unroll
    for (int r = 0; r < 4; r++){
      const int qr = qbase + quad * 4 + r;
      float aa[4];
      #pragma unroll
      for (int nt = 0; nt < 4; nt++){
        float s = s_acc[nt][r] * scale;
        if (kt0 + nt * 16 + row16 > qr) s = -3e38f;  // finite mask, NaN-free
        aa[nt] = s;
      }
      float mx = fmaxf(fmaxf(aa[0], aa[1]), fmaxf(aa[2], aa[3]));
      #pragma unroll
      for (int off = 1; off < 16; off <<= 1) mx = fmaxf(mx, __shfl_xor(mx, off, 64));
      const float mn = fmaxf(m_r[r], mx);
      alpha[r] = __expf(m_r[r] - mn);
      float ps = 0.f;
      #pragma unroll
      for (int nt = 0; nt < 4; nt++){
        const float p = __expf(aa[nt] - mn);
        ps += p;
        p_s[wave][quad * 4 + r][nt * 16 + row16] = f2bf(p);
      }
      #pragma unroll
      for (int off = 1; off < 16; off <<= 1) ps += __shfl_xor(ps, off, 64);
      l_r[r] = l_r[r] * alpha[r] + ps;
      m_r[r] = mn;
    }
    #pragma unroll
    for (int nd = 0; nd < 8; nd++)
      #pragma unroll
      for (int r = 0; r < 4; r++) o_acc[nd][r] *= alpha[r];

    asm volatile("" ::: "memory");  // keep p_s writes before reads; DS is
                                    // in-order per wave, p_s is wave-private

    // ---- O += P V ----
    #pragma unroll
    for (int kk = 0; kk < 2; kk++){
      const bf16x8 pf = *(const bf16x8*)&p_s[wave][row16][kk * 32 + quad * 8];
      #pragma unroll
      for (int nd = 0; nd < 8; nd++){
        const bf16x8 vb = *(const bf16x8*)&vt_s[nd * 16 + row16][kk * 32 + quad * 8];
        o_acc[nd] = __builtin_amdgcn_mfma_f32_16x16x32_bf16(pf, vb, o_acc[nd], 0, 0, 0);
      }
    }
    __syncthreads();   // protect k_s/vt_s restage
  }

  const int b = bh >> 4, h = bh & 15;
  #pragma unroll
  for (int nd = 0; nd < 8; nd++){
    #pragma unroll
    for (int r = 0; r < 4; r++){
      const int qr = qbase + quad * 4 + r;
      const size_t off = ((size_t)b * TT + qr) * DM + h * DH + nd * 16 + row16;
      ctx[off] = f2bf(o_acc[nd][r] / l_r[r]);
    }
  }
}

extern "C" void kernel_launch(void* const* d_in, const int* in_sizes, int n_in,
                              void* d_out, int out_size, void* d_ws, size_t ws_size,
                              hipStream_t stream){
  const float* x  = (const float*)d_in[0];   // fp32 per reference
  const float* wq = (const float*)d_in[1];
  const float* wk = (const float*)d_in[2];
  const float* wv = (const float*)d_in[3];
  const float* wo = (const float*)d_in[4];
  const int* pos  = (const int*)d_in[5];

  char* ws = (char*)d_ws;
  u16* xb = (u16*)ws;                 // 16 MB bf16 x; dead after QKV gemms
  u16* cb = xb;                       //   ...then reused as ctx buffer
  u16* wt = (u16*)(ws + 16777216);    //  8 MB transposed weight (reused)
  u16* qb = (u16*)(ws + 25165824);    // 16 MB each
  u16* kb = qb + 8388608;
  u16* vb = kb + 8388608;             // total ws use: 75,497,472 B

  const dim3 tg(64, 64), tb(32, 8);
  const dim3 gg(32, 16);

  cvt_f32_bf16<<<8192, 256, 0, stream>>>(x, xb, 2097152);

  transpose2048<<<tg, tb, 0, stream>>>(wq, wt);
  gemm_bt<<<gg, 256, 0, stream>>>(xb, wt, qb, 1);
  transpose2048<<<tg, tb, 0, stream>>>(wk, wt);
  gemm_bt<<<gg, 256, 0, stream>>>(xb, wt, kb, 1);
  transpose2048<<<tg, tb, 0, stream>>>(wv, wt);
  gemm_bt<<<gg, 256, 0, stream>>>(xb, wt, vb, 1);

  rope_inplace<<<16384, 256, 0, stream>>>(qb, pos);
  rope_inplace<<<16384, 256, 0, stream>>>(kb, pos);

  attn_fwd<<<dim3(32, 32), 256, 0, stream>>>(qb, kb, vb, cb);

  transpose2048<<<tg, tb, 0, stream>>>(wo, wt);
  gemm_bt<<<gg, 256, 0, stream>>>(cb, wt, d_out, 0);   // fp32 out [B,T,D]
}